// Round 2
// baseline (87.348 us; speedup 1.0000x reference)
//
#include <hip/hip_runtime.h>
#include <math.h>

// Problem constants (fixed by setup_inputs: N=1024, H=W=256, B=64).
#define HCONST 256
#define WCONST 256
#define NMAX   1024
#define TILE_Y 16
#define TILES  (HCONST / TILE_Y)   // 16 y-tiles per batch image

// ---------------------------------------------------------------------------
// Single fused kernel.
//
// Math: g = fx(x)*fy(y) is separable and positive, so max over the grid is
// max(fx)*max(fy), attained at the grid point nearest mu (grid step 1/255).
// The 1/(2*pi*sx*sy) prefactor cancels in g/max(g). Hence
//   g_norm[n,y,x] = pred[n] * exp(-ax*(dx^2-dxmin^2)) * exp(-ay*(dy^2-dymin^2))
// and the segment-sum is a sum of rank-1 outer products per batch.
//
// Block = one (batch, 16-row y-tile): 256 threads, one x-column each.
// Phase 1: compact this batch's gaussian indices into LDS (parallel scan of
//          batch_list, block-uniform compare -> no divergence cost).
// Phase 2: per gaussian, each thread computes ONE fx exp (its column, pred
//          folded in) and ONE fy exp (row y0 + lane%16); the 16 fy values are
//          broadcast across each 16-lane segment via __shfl(width=16).
//          16 register accumulators, one coalesced store pass at the end.
// Output written exactly once -> no pre-zero needed.
// ---------------------------------------------------------------------------
__global__ __launch_bounds__(WCONST) void fused_kernel(
    const float* __restrict__ pred,
    const float* __restrict__ nodes,      // (N,4): mux, muy, sx, sy
    const int*   __restrict__ batch_list,
    int N,
    float* __restrict__ out)
{
    const int b  = blockIdx.x / TILES;
    const int ty = blockIdx.x % TILES;
    const int y0 = ty * TILE_Y;
    const int x  = threadIdx.x;

    __shared__ int s_idx[NMAX];
    __shared__ int s_cnt;
    if (x == 0) s_cnt = 0;
    __syncthreads();
    for (int n = x; n < N; n += WCONST) {
        if (batch_list[n] == b) {
            int p = atomicAdd(&s_cnt, 1);
            s_idx[p] = n;
        }
    }
    __syncthreads();
    const int cnt = s_cnt;

    float acc[TILE_Y];
#pragma unroll
    for (int yy = 0; yy < TILE_Y; ++yy) acc[yy] = 0.0f;

    const float step  = 1.0f / 255.0f;
    const float xs    = x * step;
    const float ylane = (y0 + (x & (TILE_Y - 1))) * step;   // row this lane evaluates

    for (int g = 0; g < cnt; ++g) {
        const int n = s_idx[g];                     // LDS broadcast (uniform)
        const float4 nd = ((const float4*)nodes)[n]; // one cacheline, all lanes same
        const float pr = pred[n];

        const float ax = 1.0f / (2.0f * nd.z * nd.z);
        const float ay = 1.0f / (2.0f * nd.w * nd.w);

        // nearest grid index to mu -> minimal |d| on each axis (the grid max)
        const float nix = fminf(fmaxf(roundf(nd.x * 255.0f), 0.0f), 255.0f);
        const float niy = fminf(fmaxf(roundf(nd.y * 255.0f), 0.0f), 255.0f);
        const float dxm = nix * step - nd.x;
        const float dym = niy * step - nd.y;

        const float dx = xs - nd.x;
        const float fx = __expf(-ax * (dx * dx - dxm * dxm)) * pr;  // pred folded in

        const float dy  = ylane - nd.y;
        const float fyv = __expf(-ay * (dy * dy - dym * dym));

#pragma unroll
        for (int yy = 0; yy < TILE_Y; ++yy)
            acc[yy] = fmaf(__shfl(fyv, yy, TILE_Y), fx, acc[yy]);
    }

    float* o = out + ((size_t)b * HCONST + y0) * WCONST + x;
#pragma unroll
    for (int yy = 0; yy < TILE_Y; ++yy)
        o[yy * WCONST] = acc[yy];
}

// ---------------------------------------------------------------------------
extern "C" void kernel_launch(void* const* d_in, const int* in_sizes, int n_in,
                              void* d_out, int out_size, void* d_ws, size_t ws_size,
                              hipStream_t stream) {
    const float* pred       = (const float*)d_in[0];
    const float* nodes      = (const float*)d_in[1];
    const int*   batch_list = (const int*)d_in[2];

    const int N = in_sizes[0];                    // 1024
    const int B = out_size / (HCONST * WCONST);   // 64

    float* out = (float*)d_out;

    fused_kernel<<<B * TILES, WCONST, 0, stream>>>(pred, nodes, batch_list, N, out);
}

// Round 3
// 74.122 us; speedup vs baseline: 1.1784x; 1.1784x over previous
//
#include <hip/hip_runtime.h>
#include <math.h>

// Problem constants (fixed by setup_inputs: N=1024, H=W=256, B=64).
#define HCONST 256
#define WCONST 256
#define ROWS   32                 // rows per block (stripe)
#define TILES  (HCONST / ROWS)    // 8 stripes per batch image
#define CHUNK  64                 // gaussians processed per LDS refill

// ---------------------------------------------------------------------------
// Single fused kernel, LDS-broadcast formulation.
//
// Math: g = fx(x)*fy(y) separable & positive -> grid max = max(fx)*max(fy),
// attained at the grid point nearest mu (step 1/255); the 1/(2*pi*sx*sy)
// prefactor cancels in g/max(g). So with ax=1/(2 sx^2), cx=ax*dxmin^2:
//   g_norm[n,y,x] = pred[n] * exp(cx - ax*dx^2) * exp(cy - ay*dy^2)
// and segment-sum = per-batch sum of rank-1 outer products.
//
// Block = (batch, 32-row stripe), 256 threads. Thread owns 2 adjacent
// columns x 16 rows = 32 fp32 accumulators.
// Phase 1: compact this batch's gaussian ids into LDS (block-uniform scan).
// Phase 2 (per <=64-gaussian chunk): cooperatively precompute into LDS
//   - s_prm[g] = {mux, ax, cx}  (one float4 broadcast read per g later)
//   - s_fy[g][32] = pred * fy for the stripe's 32 rows (one exp per item)
// Phase 3: accumulate. Per gaussian per thread: 1 b128 prm read (uniform
//   broadcast), 2 fx exps, 4 b128 fy reads (uniform broadcast), 32 FMAs.
//   LDS-instr/FMA = ~1/6 vs 1/1 for the previous shfl version.
// Output written exactly once -> no pre-zero needed.
// ---------------------------------------------------------------------------
__global__ __launch_bounds__(256) void fused_kernel(
    const float* __restrict__ pred,
    const float* __restrict__ nodes,      // (N,4): mux, muy, sx, sy
    const int*   __restrict__ batch_list,
    int N,
    float* __restrict__ out)
{
    const int b  = blockIdx.x / TILES;
    const int ty = blockIdx.x % TILES;
    const int y0 = ty * ROWS;
    const int t  = threadIdx.x;
    const int xi   = t & 127;        // column pair index: x = 2*xi, 2*xi+1
    const int half = t >> 7;         // 0: rows y0..y0+15, 1: rows y0+16..y0+31

    __shared__ int    s_idx[1024];
    __shared__ int    s_cnt;
    __shared__ float4 s_prm[CHUNK];          // {mux, ax, cx, 0}
    __shared__ float  s_fy[CHUNK][ROWS];     // pred * fy, stripe rows

    if (t == 0) s_cnt = 0;
    __syncthreads();
    for (int n = t; n < N; n += 256) {
        if (batch_list[n] == b) {
            int p = atomicAdd(&s_cnt, 1);
            s_idx[p] = n;
        }
    }
    __syncthreads();
    const int cnt = s_cnt;

    const float step = 1.0f / 255.0f;
    const float x0s = (2 * xi)     * step;
    const float x1s = (2 * xi + 1) * step;

    float2 acc[16];
#pragma unroll
    for (int r = 0; r < 16; ++r) acc[r] = make_float2(0.0f, 0.0f);

    for (int c0 = 0; c0 < cnt; c0 += CHUNK) {
        const int cc = min(CHUNK, cnt - c0);

        // --- per-gaussian x-params ---
        for (int p = t; p < cc; p += 256) {
            const int n = s_idx[c0 + p];
            const float4 nd = ((const float4*)nodes)[n];
            const float ax = 1.0f / (2.0f * nd.z * nd.z);
            float ni = roundf(nd.x * 255.0f);
            ni = fminf(fmaxf(ni, 0.0f), 255.0f);
            const float dxm = ni * step - nd.x;
            s_prm[p] = make_float4(nd.x, ax, ax * dxm * dxm, 0.0f);
        }
        // --- per-gaussian fy for the stripe's 32 rows (pred folded in) ---
        for (int it = t; it < cc * ROWS; it += 256) {
            const int g  = it >> 5;
            const int yy = it & 31;
            const int n  = s_idx[c0 + g];
            const float4 nd = ((const float4*)nodes)[n];
            const float ay = 1.0f / (2.0f * nd.w * nd.w);
            float ni = roundf(nd.y * 255.0f);
            ni = fminf(fmaxf(ni, 0.0f), 255.0f);
            const float dym = ni * step - nd.y;
            const float dy  = (y0 + yy) * step - nd.y;
            s_fy[g][yy] = pred[n] * __expf(ay * (dym * dym - dy * dy));
        }
        __syncthreads();

        // --- accumulate ---
        for (int g = 0; g < cc; ++g) {
            const float4 prm = s_prm[g];                      // broadcast
            const float dx0 = x0s - prm.x;
            const float dx1 = x1s - prm.x;
            const float e0 = __expf(prm.z - prm.y * dx0 * dx0);
            const float e1 = __expf(prm.z - prm.y * dx1 * dx1);
            const float4* fy4 = (const float4*)&s_fy[g][half * 16];
#pragma unroll
            for (int k = 0; k < 4; ++k) {
                const float4 f = fy4[k];                      // broadcast b128
                acc[k*4+0].x = fmaf(f.x, e0, acc[k*4+0].x);
                acc[k*4+0].y = fmaf(f.x, e1, acc[k*4+0].y);
                acc[k*4+1].x = fmaf(f.y, e0, acc[k*4+1].x);
                acc[k*4+1].y = fmaf(f.y, e1, acc[k*4+1].y);
                acc[k*4+2].x = fmaf(f.z, e0, acc[k*4+2].x);
                acc[k*4+2].y = fmaf(f.z, e1, acc[k*4+2].y);
                acc[k*4+3].x = fmaf(f.w, e0, acc[k*4+3].x);
                acc[k*4+3].y = fmaf(f.w, e1, acc[k*4+3].y);
            }
        }
        __syncthreads();   // before next chunk overwrites s_prm/s_fy
    }

    // --- store: float2 per row, coalesced across xi ---
    float* o = out + ((size_t)b * HCONST + y0 + half * 16) * WCONST + 2 * xi;
#pragma unroll
    for (int r = 0; r < 16; ++r)
        ((float2*)(o + (size_t)r * WCONST))[0] = acc[r];
}

// ---------------------------------------------------------------------------
extern "C" void kernel_launch(void* const* d_in, const int* in_sizes, int n_in,
                              void* d_out, int out_size, void* d_ws, size_t ws_size,
                              hipStream_t stream) {
    const float* pred       = (const float*)d_in[0];
    const float* nodes      = (const float*)d_in[1];
    const int*   batch_list = (const int*)d_in[2];

    const int N = in_sizes[0];                    // 1024
    const int B = out_size / (HCONST * WCONST);   // 64

    float* out = (float*)d_out;

    fused_kernel<<<B * TILES, 256, 0, stream>>>(pred, nodes, batch_list, N, out);
}